// Round 1
// baseline (1099.452 us; speedup 1.0000x reference)
//
#include <hip/hip_runtime.h>
#include <stdint.h>
#include <stddef.h>

// Problem constants (B=1)
#define NNODES 40962
#define NBLK   161
#define NP     41216          // NBLK*256
#define DM     512
#define NH     4
#define HD     128
#define SCALE_ATT 0.08838834764831845f   // 128^-0.5

typedef __attribute__((ext_vector_type(8))) short short8;
typedef __attribute__((ext_vector_type(4))) float f32x4;
typedef __attribute__((ext_vector_type(4))) unsigned short us4;
typedef __attribute__((ext_vector_type(8))) __bf16 bf16x8;

__device__ __forceinline__ unsigned short f2bf(float f){
  unsigned u = __builtin_bit_cast(unsigned, f);
  u += 0x7fffu + ((u >> 16) & 1u);          // RNE
  return (unsigned short)(u >> 16);
}
__device__ __forceinline__ float gelu_tanh(float x){
  float t = tanhf(0.7978845608028654f * (x + 0.044715f * x * x * x));
  return 0.5f * x * (1.0f + t);
}
__device__ __forceinline__ bf16x8 ldb8(const unsigned short* p){
  return *(const bf16x8*)p;
}
#define MFMA(a,b,c) __builtin_amdgcn_mfma_f32_16x16x32_bf16((a),(b),(c),0,0,0)

// ---------------- cond: so = gnc @ w_cond + b_cond; store [scale+1 | offset] ----
__global__ void k_cond(const float* __restrict__ gnc, const float* __restrict__ wc,
                       const float* __restrict__ bc, float* __restrict__ cond){
  int j = blockIdx.x * 256 + threadIdx.x;   // 0..1023
  float acc = bc[j];
  #pragma unroll
  for(int c = 0; c < 16; ++c) acc += gnc[c] * wc[c * 1024 + j];
  cond[j] = (j < 512) ? acc + 1.0f : acc;
}

// ---------------- W[K][N] fp32 -> Wt[N][K] bf16 (K,N multiples of 32) ----------
__global__ __launch_bounds__(256) void k_transpose(const float* __restrict__ W,
                                                   unsigned short* __restrict__ Wt,
                                                   int K, int Ncols){
  __shared__ float tile[32][33];
  int n0 = blockIdx.x * 32, k0 = blockIdx.y * 32;
  int tx = threadIdx.x & 31, ty = threadIdx.x >> 5;
  #pragma unroll
  for(int i = 0; i < 4; ++i){
    int r = ty + i * 8;
    tile[r][tx] = W[(size_t)(k0 + r) * Ncols + n0 + tx];
  }
  __syncthreads();
  #pragma unroll
  for(int i = 0; i < 4; ++i){
    int r = ty + i * 8;
    Wt[(size_t)(n0 + r) * K + k0 + tx] = f2bf(tile[tx][r]);
  }
}

// ---------------- LayerNorm + cond -> bf16, rows >= Mvalid zeroed --------------
__global__ __launch_bounds__(256) void k_lncond(const float* __restrict__ x,
                                                const float* __restrict__ cond,
                                                unsigned short* __restrict__ out, int Mvalid){
  int lane = threadIdx.x & 63;
  int row = blockIdx.x * 4 + (threadIdx.x >> 6);
  unsigned short* orow = out + (size_t)row * DM + lane * 8;
  if(row >= Mvalid){
    *(uint4*)orow = make_uint4(0,0,0,0);
    return;
  }
  const float* xr = x + (size_t)row * DM + lane * 8;
  float4 a = *(const float4*)xr;
  float4 b = *(const float4*)(xr + 4);
  float v[8] = {a.x,a.y,a.z,a.w,b.x,b.y,b.z,b.w};
  float s = 0.f, s2 = 0.f;
  #pragma unroll
  for(int j = 0; j < 8; ++j){ s += v[j]; s2 += v[j]*v[j]; }
  #pragma unroll
  for(int off = 1; off < 64; off <<= 1){ s += __shfl_xor(s, off); s2 += __shfl_xor(s2, off); }
  float mu = s * (1.f/DM);
  float var = s2 * (1.f/DM) - mu*mu;
  float rs = rsqrtf(var + 1e-5f);
  float4 sc0 = *(const float4*)(cond + lane*8);
  float4 sc1 = *(const float4*)(cond + lane*8 + 4);
  float4 of0 = *(const float4*)(cond + 512 + lane*8);
  float4 of1 = *(const float4*)(cond + 512 + lane*8 + 4);
  float scv[8] = {sc0.x,sc0.y,sc0.z,sc0.w,sc1.x,sc1.y,sc1.z,sc1.w};
  float ofv[8] = {of0.x,of0.y,of0.z,of0.w,of1.x,of1.y,of1.z,of1.w};
  unsigned pk[4];
  #pragma unroll
  for(int j = 0; j < 4; ++j){
    float o0 = (v[2*j]   - mu) * rs * scv[2*j]   + ofv[2*j];
    float o1 = (v[2*j+1] - mu) * rs * scv[2*j+1] + ofv[2*j+1];
    pk[j] = (unsigned)f2bf(o0) | ((unsigned)f2bf(o1) << 16);
  }
  *(uint4*)orow = make_uint4(pk[0],pk[1],pk[2],pk[3]);
}

// ---------------- generic bf16 GEMM: C[M,N] = A[M,K] @ Bt[N,K]^T ---------------
#define GF_GELU  1
#define GF_F32   2
#define GF_TRANS 4

__global__ __launch_bounds__(256, 2)
void k_gemm(const unsigned short* __restrict__ A, int lda, int Arows,
            const unsigned short* __restrict__ Bt, int ldb,
            const float* __restrict__ bias,
            const float* __restrict__ resid, int ldr,
            void* __restrict__ out, int ldo,
            int Mstore, int Ksteps, int flags)
{
  __shared__ __align__(16) unsigned short As[128*72];
  __shared__ __align__(16) unsigned short Bs[128*72];
  int tid = threadIdx.x;
  int lane = tid & 63, l15 = lane & 15, lg = lane >> 4;
  int wm = (tid >> 7) & 1, wn = (tid >> 6) & 1;
  int m0 = blockIdx.x * 128, n0 = blockIdx.y * 128;
  f32x4 acc[4][4];
  #pragma unroll
  for(int i = 0; i < 4; ++i)
    #pragma unroll
    for(int j = 0; j < 4; ++j) acc[i][j] = (f32x4)0.0f;
  short8 zero8 = (short8)(short)0;

  for(int ks = 0; ks < Ksteps; ++ks){
    #pragma unroll
    for(int i = 0; i < 4; ++i){
      int c = tid + i * 256;
      int row = c >> 3, cs = (c & 7) * 8;
      short8 va = zero8;
      if(m0 + row < Arows) va = *(const short8*)(A + (size_t)(m0+row)*lda + ks*64 + cs);
      *(short8*)(As + row*72 + cs) = va;
      *(short8*)(Bs + row*72 + cs) = *(const short8*)(Bt + (size_t)(n0+row)*ldb + ks*64 + cs);
    }
    __syncthreads();
    #pragma unroll
    for(int kk = 0; kk < 2; ++kk){
      bf16x8 la[4], lb[4];
      #pragma unroll
      for(int mi = 0; mi < 4; ++mi) la[mi] = ldb8(As + (wm*64 + mi*16 + l15)*72 + kk*32 + lg*8);
      #pragma unroll
      for(int ni = 0; ni < 4; ++ni) lb[ni] = ldb8(Bs + (wn*64 + ni*16 + l15)*72 + kk*32 + lg*8);
      #pragma unroll
      for(int mi = 0; mi < 4; ++mi)
        #pragma unroll
        for(int ni = 0; ni < 4; ++ni)
          acc[mi][ni] = MFMA(la[mi], lb[ni], acc[mi][ni]);
    }
    __syncthreads();
  }
  // epilogue
  #pragma unroll
  for(int mi = 0; mi < 4; ++mi){
    #pragma unroll
    for(int ni = 0; ni < 4; ++ni){
      int col = n0 + wn*64 + ni*16 + l15;
      float bc = bias ? bias[col] : 0.f;
      float vv[4];
      #pragma unroll
      for(int r = 0; r < 4; ++r){
        float t = acc[mi][ni][r] + bc;
        if(flags & GF_GELU) t = gelu_tanh(t);
        vv[r] = t;
      }
      int rowb = m0 + wm*64 + mi*16 + lg*4;
      if(flags & GF_TRANS){
        us4 pk;
        #pragma unroll
        for(int r = 0; r < 4; ++r) pk[r] = f2bf(vv[r]);
        *(us4*)((unsigned short*)out + (size_t)col*ldo + rowb) = pk;
      } else {
        #pragma unroll
        for(int r = 0; r < 4; ++r){
          int row = rowb + r;
          if(row < Mstore){
            float t = vv[r];
            if(resid) t += resid[(size_t)row*ldr + col];
            if(flags & GF_F32) ((float*)out)[(size_t)row*ldo + col] = t;
            else ((unsigned short*)out)[(size_t)row*ldo + col] = f2bf(t);
          }
        }
      }
    }
  }
}

// ---------------- tri-block flash attention --------------------------------
// grid (NBLK, 2, NH), 512 threads (8 waves). Wave w owns q rows
// [n*256 + rg*128 + w*16, +16). K tile and Vt tile share one LDS buffer.
__global__ __launch_bounds__(512, 2)
void k_attn(const unsigned short* __restrict__ q_g, const unsigned short* __restrict__ k_g,
            const unsigned short* __restrict__ vt_g, unsigned short* __restrict__ o_g)
{
  __shared__ __align__(16) unsigned short kv[256*136];      // K:[256][136]  Vt:[128][264]
  __shared__ __align__(16) unsigned short p_lds[8*16*264];  // per-wave P[q16][key256] padded
  int n = blockIdx.x, rg = blockIdx.y, h = blockIdx.z;
  int tid = threadIdx.x;
  int w = tid >> 6, lane = tid & 63, l15 = lane & 15, lg = lane >> 4;
  int qbase = n*256 + rg*128 + w*16;
  unsigned short* pw = p_lds + w*16*264;

  bf16x8 aq[4];
  {
    const unsigned short* qp = q_g + (size_t)(qbase + l15)*DM + h*HD + lg*8;
    #pragma unroll
    for(int kb = 0; kb < 4; ++kb) aq[kb] = ldb8(qp + kb*32);
  }
  f32x4 oacc[8];
  #pragma unroll
  for(int t = 0; t < 8; ++t) oacc[t] = (f32x4)0.0f;
  float mrun[4] = {-1e30f,-1e30f,-1e30f,-1e30f};
  float denom[4] = {0.f,0.f,0.f,0.f};

  #pragma unroll 1
  for(int d = 0; d < 3; ++d){
    int nb = n + (d == 1 ? 1 : (d == 2 ? -1 : 0));
    if(nb < 0 || nb >= NBLK) continue;          // uniform across block
    __syncthreads();                            // prior Vt reads done
    for(int i = 0; i < 8; ++i){                 // stage K tile 256x128 -> [256][136]
      int c = tid + i*512;
      int row = c >> 4, cs = (c & 15) * 8;
      *(short8*)(kv + row*136 + cs) = *(const short8*)(k_g + (size_t)(nb*256+row)*DM + h*HD + cs);
    }
    __syncthreads();
    // S[q16 x key256] = q @ k^T
    f32x4 st[16];
    #pragma unroll
    for(int t = 0; t < 16; ++t){
      f32x4 s = (f32x4)0.0f;
      #pragma unroll
      for(int kb = 0; kb < 4; ++kb){
        bf16x8 bk = ldb8(kv + (t*16 + l15)*136 + kb*32 + lg*8);
        s = MFMA(aq[kb], bk, s);
      }
      st[t] = s;
    }
    // mask (key index < N) + scale + row max
    float rmax[4] = {-1e30f,-1e30f,-1e30f,-1e30f};
    #pragma unroll
    for(int t = 0; t < 16; ++t){
      bool kval = (nb*256 + t*16 + l15) < NNODES;
      #pragma unroll
      for(int r = 0; r < 4; ++r){
        float sv = kval ? st[t][r] * SCALE_ATT : -1e30f;
        st[t][r] = sv;
        rmax[r] = fmaxf(rmax[r], sv);
      }
    }
    #pragma unroll
    for(int r = 0; r < 4; ++r){
      float m = rmax[r];
      m = fmaxf(m, __shfl_xor(m, 1));
      m = fmaxf(m, __shfl_xor(m, 2));
      m = fmaxf(m, __shfl_xor(m, 4));
      m = fmaxf(m, __shfl_xor(m, 8));
      float mnew = fmaxf(mrun[r], m);
      float al = expf(mrun[r] - mnew);
      mrun[r] = mnew;
      denom[r] *= al;
      rmax[r] = al;                              // reuse as alpha
    }
    float rsum[4] = {0.f,0.f,0.f,0.f};
    #pragma unroll
    for(int t = 0; t < 16; ++t){
      #pragma unroll
      for(int r = 0; r < 4; ++r){
        float p = expf(st[t][r] - mrun[r]);      // masked -> exp(-1e30) = 0
        rsum[r] += p;
        pw[(lg*4 + r)*264 + t*16 + l15] = f2bf(p);
      }
    }
    #pragma unroll
    for(int r = 0; r < 4; ++r){
      float s_ = rsum[r];
      s_ += __shfl_xor(s_, 1); s_ += __shfl_xor(s_, 2);
      s_ += __shfl_xor(s_, 4); s_ += __shfl_xor(s_, 8);
      denom[r] += s_;
    }
    #pragma unroll
    for(int t = 0; t < 8; ++t){
      f32x4 o = oacc[t];
      o[0]*=rmax[0]; o[1]*=rmax[1]; o[2]*=rmax[2]; o[3]*=rmax[3];
      oacc[t] = o;
    }
    __syncthreads();                            // all waves done with K tile + P written
    for(int i = 0; i < 8; ++i){                 // stage Vt tile 128x256 -> [128][264]
      int c = tid + i*512;
      int row = c >> 5, cs = (c & 31) * 8;
      *(short8*)(kv + row*264 + cs) = *(const short8*)(vt_g + (size_t)(h*HD+row)*NP + nb*256 + cs);
    }
    __syncthreads();
    // O += P @ V
    #pragma unroll
    for(int kb2 = 0; kb2 < 8; ++kb2){
      bf16x8 ap = ldb8(pw + l15*264 + kb2*32 + lg*8);
      #pragma unroll
      for(int t2 = 0; t2 < 8; ++t2){
        bf16x8 bv = ldb8(kv + (t2*16 + l15)*264 + kb2*32 + lg*8);
        oacc[t2] = MFMA(ap, bv, oacc[t2]);
      }
    }
  }
  float inv[4];
  #pragma unroll
  for(int r = 0; r < 4; ++r) inv[r] = 1.0f / denom[r];
  #pragma unroll
  for(int t2 = 0; t2 < 8; ++t2){
    #pragma unroll
    for(int r = 0; r < 4; ++r){
      o_g[(size_t)(qbase + lg*4 + r)*DM + h*HD + t2*16 + l15] = f2bf(oacc[t2][r] * inv[r]);
    }
  }
}

// ---------------- host orchestration ----------------------------------------
extern "C" void kernel_launch(void* const* d_in, const int* in_sizes, int n_in,
                              void* d_out, int out_size, void* d_ws, size_t ws_size,
                              hipStream_t stream)
{
  const float* x    = (const float*)d_in[0];
  const float* gnc  = (const float*)d_in[1];
  // d_in[2] = mask : unused (computed analytically)
  const float* wq   = (const float*)d_in[3];
  const float* wk   = (const float*)d_in[4];
  const float* wv   = (const float*)d_in[5];
  const float* wf   = (const float*)d_in[6];
  const float* bfin = (const float*)d_in[7];
  const float* wup  = (const float*)d_in[8];
  const float* bup  = (const float*)d_in[9];
  const float* wdn  = (const float*)d_in[10];
  const float* bdn  = (const float*)d_in[11];
  const float* wc   = (const float*)d_in[12];
  const float* bc   = (const float*)d_in[13];
  float* out = (float*)d_out;

  char* ws = (char*)d_ws;
  size_t off = 0;
  auto alloc = [&](size_t bytes)->void*{
    void* p = ws + off;
    off += (bytes + 255) & ~(size_t)255;
    return p;
  };
  float*          cond  = (float*)alloc(1024u*4);
  unsigned short* wq_t  = (unsigned short*)alloc((size_t)512*512*2);
  unsigned short* wk_t  = (unsigned short*)alloc((size_t)512*512*2);
  unsigned short* wv_t  = (unsigned short*)alloc((size_t)512*512*2);
  unsigned short* wf_t  = (unsigned short*)alloc((size_t)512*512*2);
  unsigned short* wup_t = (unsigned short*)alloc((size_t)2048*512*2);
  unsigned short* wdn_t = (unsigned short*)alloc((size_t)512*2048*2);
  unsigned short* hp    = (unsigned short*)alloc((size_t)NP*DM*2);   // also o, also u lo-half
  unsigned short* kbuf  = (unsigned short*)alloc((size_t)NP*DM*2);   // also u hi-half
  unsigned short* vtbuf = (unsigned short*)alloc((size_t)NP*DM*2);
  unsigned short* qbuf  = (unsigned short*)alloc((size_t)NP*DM*2);   // also h2
  float*          x1    = (float*)alloc((size_t)NNODES*DM*4);
  unsigned short* ubuf  = hp;   // [41216][1024] bf16 overlays hp+kbuf exactly
  (void)ws_size; (void)in_sizes; (void)n_in; (void)out_size;

  // cond vector
  k_cond<<<4, 256, 0, stream>>>(gnc, wc, bc, cond);
  // weight transposes (fp32 -> bf16 [N][K])
  k_transpose<<<dim3(16,16), 256, 0, stream>>>(wq,  wq_t,  512, 512);
  k_transpose<<<dim3(16,16), 256, 0, stream>>>(wk,  wk_t,  512, 512);
  k_transpose<<<dim3(16,16), 256, 0, stream>>>(wv,  wv_t,  512, 512);
  k_transpose<<<dim3(16,16), 256, 0, stream>>>(wf,  wf_t,  512, 512);
  k_transpose<<<dim3(64,16), 256, 0, stream>>>(wup, wup_t, 512, 2048);
  k_transpose<<<dim3(16,64), 256, 0, stream>>>(wdn, wdn_t, 2048, 512);
  // LN1 + cond -> hp (pad rows zero)
  k_lncond<<<NP/4, 256, 0, stream>>>(x, cond, hp, NNODES);
  // QKV projections
  k_gemm<<<dim3(322,4), 256, 0, stream>>>(hp, 512, NP, wq_t, 512, nullptr, nullptr, 0,
                                          qbuf, 512, NP, 8, 0);
  k_gemm<<<dim3(322,4), 256, 0, stream>>>(hp, 512, NP, wk_t, 512, nullptr, nullptr, 0,
                                          kbuf, 512, NP, 8, 0);
  k_gemm<<<dim3(322,4), 256, 0, stream>>>(hp, 512, NP, wv_t, 512, nullptr, nullptr, 0,
                                          vtbuf, NP, NP, 8, GF_TRANS);
  // attention (writes o into hp)
  k_attn<<<dim3(NBLK,2,NH), 512, 0, stream>>>(qbuf, kbuf, vtbuf, hp);
  // final projection + residual -> x1 (fp32)
  k_gemm<<<dim3(322,4), 256, 0, stream>>>(hp, 512, NP, wf_t, 512, bfin, x, 512,
                                          x1, 512, NNODES, 8, GF_F32);
  // LN2 + cond -> h2 (qbuf), pad rows zero
  k_lncond<<<NP/4, 256, 0, stream>>>(x1, cond, qbuf, NNODES);
  // FFW in two 1024-wide halves (u overlays hp+kbuf)
  k_gemm<<<dim3(322,8), 256, 0, stream>>>(qbuf, 512, NP, wup_t, 512, bup, nullptr, 0,
                                          ubuf, 1024, NP, 8, GF_GELU);
  k_gemm<<<dim3(321,4), 256, 0, stream>>>(ubuf, 1024, NNODES, wdn_t, 2048, bdn, x1, 512,
                                          out, 512, NNODES, 16, GF_F32);
  k_gemm<<<dim3(322,8), 256, 0, stream>>>(qbuf, 512, NP, wup_t + (size_t)1024*512, 512,
                                          bup + 1024, nullptr, 0,
                                          ubuf, 1024, NP, 8, GF_GELU);
  k_gemm<<<dim3(321,4), 256, 0, stream>>>(ubuf, 1024, NNODES, wdn_t + 1024, 2048, nullptr,
                                          out, 512, out, 512, NNODES, 16, GF_F32);
}

// Round 2
// 1018.902 us; speedup vs baseline: 1.0791x; 1.0791x over previous
//
#include <hip/hip_runtime.h>
#include <stdint.h>
#include <stddef.h>

// Problem constants (B=1)
#define NNODES 40962
#define NBLK   161
#define NP     41216          // NBLK*256
#define DM     512
#define NH     4
#define HD     128
#define SCALE_ATT 0.08838834764831845f   // 128^-0.5

typedef __attribute__((ext_vector_type(8))) short short8;
typedef __attribute__((ext_vector_type(4))) float f32x4;
typedef __attribute__((ext_vector_type(4))) unsigned short us4;
typedef __attribute__((ext_vector_type(8))) __bf16 bf16x8;

__device__ __forceinline__ unsigned short f2bf(float f){
  unsigned u = __builtin_bit_cast(unsigned, f);
  u += 0x7fffu + ((u >> 16) & 1u);          // RNE
  return (unsigned short)(u >> 16);
}
__device__ __forceinline__ float gelu_tanh(float x){
  float t = tanhf(0.7978845608028654f * (x + 0.044715f * x * x * x));
  return 0.5f * x * (1.0f + t);
}
__device__ __forceinline__ bf16x8 ldb8(const unsigned short* p){
  return *(const bf16x8*)p;
}
#define MFMA(a,b,c) __builtin_amdgcn_mfma_f32_16x16x32_bf16((a),(b),(c),0,0,0)

// async global->LDS, 16B per lane; lds base must be wave-uniform
#define GLOAD16(g, l) \
  __builtin_amdgcn_global_load_lds((const __attribute__((address_space(1))) unsigned int*)(g), \
                                   (__attribute__((address_space(3))) unsigned int*)(l), 16, 0, 0)

// ---------------- cond: so = gnc @ w_cond + b_cond; store [scale+1 | offset] ----
__global__ void k_cond(const float* __restrict__ gnc, const float* __restrict__ wc,
                       const float* __restrict__ bc, float* __restrict__ cond){
  int j = blockIdx.x * 256 + threadIdx.x;   // 0..1023
  float acc = bc[j];
  #pragma unroll
  for(int c = 0; c < 16; ++c) acc += gnc[c] * wc[c * 1024 + j];
  cond[j] = (j < 512) ? acc + 1.0f : acc;
}

// ---------------- W[K][N] fp32 -> Wt[N][K] bf16 (K,N multiples of 32) ----------
__global__ __launch_bounds__(256) void k_transpose(const float* __restrict__ W,
                                                   unsigned short* __restrict__ Wt,
                                                   int K, int Ncols){
  __shared__ float tile[32][33];
  int n0 = blockIdx.x * 32, k0 = blockIdx.y * 32;
  int tx = threadIdx.x & 31, ty = threadIdx.x >> 5;
  #pragma unroll
  for(int i = 0; i < 4; ++i){
    int r = ty + i * 8;
    tile[r][tx] = W[(size_t)(k0 + r) * Ncols + n0 + tx];
  }
  __syncthreads();
  #pragma unroll
  for(int i = 0; i < 4; ++i){
    int r = ty + i * 8;
    Wt[(size_t)(n0 + r) * K + k0 + tx] = f2bf(tile[tx][r]);
  }
}

// ---------------- LayerNorm + cond -> bf16, rows >= Mvalid zeroed --------------
__global__ __launch_bounds__(256) void k_lncond(const float* __restrict__ x,
                                                const float* __restrict__ cond,
                                                unsigned short* __restrict__ out, int Mvalid){
  int lane = threadIdx.x & 63;
  int row = blockIdx.x * 4 + (threadIdx.x >> 6);
  unsigned short* orow = out + (size_t)row * DM + lane * 8;
  if(row >= Mvalid){
    *(uint4*)orow = make_uint4(0,0,0,0);
    return;
  }
  const float* xr = x + (size_t)row * DM + lane * 8;
  float4 a = *(const float4*)xr;
  float4 b = *(const float4*)(xr + 4);
  float v[8] = {a.x,a.y,a.z,a.w,b.x,b.y,b.z,b.w};
  float s = 0.f, s2 = 0.f;
  #pragma unroll
  for(int j = 0; j < 8; ++j){ s += v[j]; s2 += v[j]*v[j]; }
  #pragma unroll
  for(int off = 1; off < 64; off <<= 1){ s += __shfl_xor(s, off); s2 += __shfl_xor(s2, off); }
  float mu = s * (1.f/DM);
  float var = s2 * (1.f/DM) - mu*mu;
  float rs = rsqrtf(var + 1e-5f);
  float4 sc0 = *(const float4*)(cond + lane*8);
  float4 sc1 = *(const float4*)(cond + lane*8 + 4);
  float4 of0 = *(const float4*)(cond + 512 + lane*8);
  float4 of1 = *(const float4*)(cond + 512 + lane*8 + 4);
  float scv[8] = {sc0.x,sc0.y,sc0.z,sc0.w,sc1.x,sc1.y,sc1.z,sc1.w};
  float ofv[8] = {of0.x,of0.y,of0.z,of0.w,of1.x,of1.y,of1.z,of1.w};
  unsigned pk[4];
  #pragma unroll
  for(int j = 0; j < 4; ++j){
    float o0 = (v[2*j]   - mu) * rs * scv[2*j]   + ofv[2*j];
    float o1 = (v[2*j+1] - mu) * rs * scv[2*j+1] + ofv[2*j+1];
    pk[j] = (unsigned)f2bf(o0) | ((unsigned)f2bf(o1) << 16);
  }
  *(uint4*)orow = make_uint4(pk[0],pk[1],pk[2],pk[3]);
}

// ---------------- m97-style bf16 GEMM: C[M,N] = A[M,K] @ Bt[N,K]^T -------------
// Requires: M multiple of 128 (A fully addressable), N,K multiples of 128/64.
#define GF_GELU  1
#define GF_F32   2
#define GF_TRANS 4

__global__ __launch_bounds__(256, 2)
void k_gemm(const unsigned short* __restrict__ A, int lda,
            const unsigned short* __restrict__ Bt, int ldb,
            const float* __restrict__ bias,
            const float* __restrict__ resid, int ldr,
            void* __restrict__ out, int ldo,
            int Mstore, int Ksteps, int flags)
{
  __shared__ __align__(16) unsigned short As[128*64];
  __shared__ __align__(16) unsigned short Bs[128*64];
  int tid = threadIdx.x;
  int lane = tid & 63, l15 = lane & 15, lg = lane >> 4;
  int w = tid >> 6;
  int wm = (tid >> 7) & 1, wn = (tid >> 6) & 1;
  int m0 = blockIdx.x * 128, n0 = blockIdx.y * 128;
  f32x4 acc[4][4];
  #pragma unroll
  for(int i = 0; i < 4; ++i)
    #pragma unroll
    for(int j = 0; j < 4; ++j) acc[i][j] = (f32x4)0.0f;

  for(int ks = 0; ks < Ksteps; ++ks){
    #pragma unroll
    for(int i = 0; i < 4; ++i){
      int cbase = i * 256 + w * 64;          // wave-uniform
      int c = cbase + lane;
      GLOAD16(A  + (size_t)(m0 + (c >> 3)) * lda + ks*64 + (c & 7) * 8, As + cbase * 8);
      GLOAD16(Bt + (size_t)(n0 + (c >> 3)) * ldb + ks*64 + (c & 7) * 8, Bs + cbase * 8);
    }
    __syncthreads();
    #pragma unroll
    for(int kk = 0; kk < 2; ++kk){
      bf16x8 la[4], lb[4];
      #pragma unroll
      for(int mi = 0; mi < 4; ++mi) la[mi] = ldb8(As + (wm*64 + mi*16 + l15)*64 + kk*32 + lg*8);
      #pragma unroll
      for(int ni = 0; ni < 4; ++ni) lb[ni] = ldb8(Bs + (wn*64 + ni*16 + l15)*64 + kk*32 + lg*8);
      #pragma unroll
      for(int mi = 0; mi < 4; ++mi)
        #pragma unroll
        for(int ni = 0; ni < 4; ++ni)
          acc[mi][ni] = MFMA(la[mi], lb[ni], acc[mi][ni]);
    }
    __syncthreads();
  }
  // epilogue
  #pragma unroll
  for(int mi = 0; mi < 4; ++mi){
    #pragma unroll
    for(int ni = 0; ni < 4; ++ni){
      int col = n0 + wn*64 + ni*16 + l15;
      float bc = bias ? bias[col] : 0.f;
      float vv[4];
      #pragma unroll
      for(int r = 0; r < 4; ++r){
        float t = acc[mi][ni][r] + bc;
        if(flags & GF_GELU) t = gelu_tanh(t);
        vv[r] = t;
      }
      int rowb = m0 + wm*64 + mi*16 + lg*4;
      if(flags & GF_TRANS){
        us4 pk;
        #pragma unroll
        for(int r = 0; r < 4; ++r) pk[r] = f2bf(vv[r]);
        *(us4*)((unsigned short*)out + (size_t)col*ldo + rowb) = pk;
      } else {
        #pragma unroll
        for(int r = 0; r < 4; ++r){
          int row = rowb + r;
          if(row < Mstore){
            float t = vv[r];
            if(resid) t += resid[(size_t)row*ldr + col];
            if(flags & GF_F32) ((float*)out)[(size_t)row*ldo + col] = t;
            else ((unsigned short*)out)[(size_t)row*ldo + col] = f2bf(t);
          }
        }
      }
    }
  }
}

// ---------------- tri-block flash attention (128-key chunks) -----------------
// grid (NBLK, 2, NH), 512 threads (8 waves). Wave w owns q rows
// [n*256 + rg*128 + w*16, +16). LDS: shared K/Vt chunk buffer + per-wave P.
__global__ __launch_bounds__(512, 4)
void k_attn(const unsigned short* __restrict__ q_g, const unsigned short* __restrict__ k_g,
            const unsigned short* __restrict__ vt_g, unsigned short* __restrict__ o_g)
{
  __shared__ __align__(16) unsigned short kv[128*136];      // K chunk [128][136] / Vt chunk [128][136]
  __shared__ __align__(16) unsigned short p_lds[8*16*136];  // per-wave P[q16][key128] padded
  int n = blockIdx.x, rg = blockIdx.y, h = blockIdx.z;
  int tid = threadIdx.x;
  int w = tid >> 6, lane = tid & 63, l15 = lane & 15, lg = lane >> 4;
  int qbase = n*256 + rg*128 + w*16;
  unsigned short* pw = p_lds + w*16*136;

  bf16x8 aq[4];
  {
    const unsigned short* qp = q_g + (size_t)(qbase + l15)*DM + h*HD + lg*8;
    #pragma unroll
    for(int kb = 0; kb < 4; ++kb) aq[kb] = ldb8(qp + kb*32);
  }
  f32x4 oacc[8];
  #pragma unroll
  for(int t = 0; t < 8; ++t) oacc[t] = (f32x4)0.0f;
  float mrun[4] = {-1e30f,-1e30f,-1e30f,-1e30f};
  float denom[4] = {0.f,0.f,0.f,0.f};

  #pragma unroll 1
  for(int d = 0; d < 3; ++d){
    int nb = n + (d == 1 ? 1 : (d == 2 ? -1 : 0));
    if(nb < 0 || nb >= NBLK) continue;          // uniform across block
    #pragma unroll 1
    for(int ch = 0; ch < 2; ++ch){
      int k0 = nb*256 + ch*128;
      if(k0 >= NNODES) continue;                // fully-masked chunk, uniform
      __syncthreads();                          // prior Vt reads done
      #pragma unroll
      for(int i = 0; i < 4; ++i){               // stage K chunk 128x128 -> [128][136]
        int c = tid + i*512;
        int row = c >> 4, cs = (c & 15) * 8;
        *(short8*)(kv + row*136 + cs) = *(const short8*)(k_g + (size_t)(k0+row)*DM + h*HD + cs);
      }
      __syncthreads();
      // S[q16 x key128] = q @ k^T
      f32x4 st[8];
      #pragma unroll
      for(int t = 0; t < 8; ++t){
        f32x4 s = (f32x4)0.0f;
        #pragma unroll
        for(int kb = 0; kb < 4; ++kb){
          bf16x8 bk = ldb8(kv + (t*16 + l15)*136 + kb*32 + lg*8);
          s = MFMA(aq[kb], bk, s);
        }
        st[t] = s;
      }
      // mask (key index < N) + scale + row max
      float rmax[4] = {-1e30f,-1e30f,-1e30f,-1e30f};
      #pragma unroll
      for(int t = 0; t < 8; ++t){
        bool kval = (k0 + t*16 + l15) < NNODES;
        #pragma unroll
        for(int r = 0; r < 4; ++r){
          float sv = kval ? st[t][r] * SCALE_ATT : -1e30f;
          st[t][r] = sv;
          rmax[r] = fmaxf(rmax[r], sv);
        }
      }
      #pragma unroll
      for(int r = 0; r < 4; ++r){
        float m = rmax[r];
        m = fmaxf(m, __shfl_xor(m, 1));
        m = fmaxf(m, __shfl_xor(m, 2));
        m = fmaxf(m, __shfl_xor(m, 4));
        m = fmaxf(m, __shfl_xor(m, 8));
        float mnew = fmaxf(mrun[r], m);
        float al = expf(mrun[r] - mnew);
        mrun[r] = mnew;
        denom[r] *= al;
        rmax[r] = al;                            // reuse as alpha
      }
      float rsum[4] = {0.f,0.f,0.f,0.f};
      #pragma unroll
      for(int t = 0; t < 8; ++t){
        #pragma unroll
        for(int r = 0; r < 4; ++r){
          float p = expf(st[t][r] - mrun[r]);    // masked -> 0
          rsum[r] += p;
          pw[(lg*4 + r)*136 + t*16 + l15] = f2bf(p);
        }
      }
      #pragma unroll
      for(int r = 0; r < 4; ++r){
        float s_ = rsum[r];
        s_ += __shfl_xor(s_, 1); s_ += __shfl_xor(s_, 2);
        s_ += __shfl_xor(s_, 4); s_ += __shfl_xor(s_, 8);
        denom[r] += s_;
      }
      #pragma unroll
      for(int t = 0; t < 8; ++t){
        f32x4 o = oacc[t];
        o[0]*=rmax[0]; o[1]*=rmax[1]; o[2]*=rmax[2]; o[3]*=rmax[3];
        oacc[t] = o;
      }
      __syncthreads();                          // all waves done with K chunk
      #pragma unroll
      for(int i = 0; i < 4; ++i){               // stage Vt chunk 128x128 -> [128][136]
        int c = tid + i*512;
        int row = c >> 4, cs = (c & 15) * 8;
        *(short8*)(kv + row*136 + cs) = *(const short8*)(vt_g + (size_t)(h*HD+row)*NP + k0 + cs);
      }
      __syncthreads();
      // O += P @ V
      #pragma unroll
      for(int kb2 = 0; kb2 < 4; ++kb2){
        bf16x8 ap = ldb8(pw + l15*136 + kb2*32 + lg*8);
        #pragma unroll
        for(int t2 = 0; t2 < 8; ++t2){
          bf16x8 bv = ldb8(kv + (t2*16 + l15)*136 + kb2*32 + lg*8);
          oacc[t2] = MFMA(ap, bv, oacc[t2]);
        }
      }
    }
  }
  float inv[4];
  #pragma unroll
  for(int r = 0; r < 4; ++r) inv[r] = 1.0f / denom[r];
  #pragma unroll
  for(int t2 = 0; t2 < 8; ++t2){
    #pragma unroll
    for(int r = 0; r < 4; ++r){
      o_g[(size_t)(qbase + lg*4 + r)*DM + h*HD + t2*16 + l15] = f2bf(oacc[t2][r] * inv[r]);
    }
  }
}

// ---------------- host orchestration ----------------------------------------
extern "C" void kernel_launch(void* const* d_in, const int* in_sizes, int n_in,
                              void* d_out, int out_size, void* d_ws, size_t ws_size,
                              hipStream_t stream)
{
  const float* x    = (const float*)d_in[0];
  const float* gnc  = (const float*)d_in[1];
  // d_in[2] = mask : unused (computed analytically)
  const float* wq   = (const float*)d_in[3];
  const float* wk   = (const float*)d_in[4];
  const float* wv   = (const float*)d_in[5];
  const float* wf   = (const float*)d_in[6];
  const float* bfin = (const float*)d_in[7];
  const float* wup  = (const float*)d_in[8];
  const float* bup  = (const float*)d_in[9];
  const float* wdn  = (const float*)d_in[10];
  const float* bdn  = (const float*)d_in[11];
  const float* wc   = (const float*)d_in[12];
  const float* bc   = (const float*)d_in[13];
  float* out = (float*)d_out;

  char* ws = (char*)d_ws;
  size_t off = 0;
  auto alloc = [&](size_t bytes)->void*{
    void* p = ws + off;
    off += (bytes + 255) & ~(size_t)255;
    return p;
  };
  float*          cond  = (float*)alloc(1024u*4);
  unsigned short* wq_t  = (unsigned short*)alloc((size_t)512*512*2);
  unsigned short* wk_t  = (unsigned short*)alloc((size_t)512*512*2);
  unsigned short* wv_t  = (unsigned short*)alloc((size_t)512*512*2);
  unsigned short* wf_t  = (unsigned short*)alloc((size_t)512*512*2);
  unsigned short* wup_t = (unsigned short*)alloc((size_t)2048*512*2);
  unsigned short* wdn_t = (unsigned short*)alloc((size_t)512*2048*2);
  unsigned short* hp    = (unsigned short*)alloc((size_t)NP*DM*2);   // also o, also u lo-half
  unsigned short* kbuf  = (unsigned short*)alloc((size_t)NP*DM*2);   // also u hi-half
  unsigned short* vtbuf = (unsigned short*)alloc((size_t)NP*DM*2);
  unsigned short* qbuf  = (unsigned short*)alloc((size_t)NP*DM*2);   // also h2
  float*          x1    = (float*)alloc((size_t)NNODES*DM*4);
  unsigned short* ubuf  = hp;   // [41216][1024] bf16 overlays hp+kbuf exactly
  (void)ws_size; (void)in_sizes; (void)n_in; (void)out_size;

  // cond vector
  k_cond<<<4, 256, 0, stream>>>(gnc, wc, bc, cond);
  // weight transposes (fp32 -> bf16 [N][K])
  k_transpose<<<dim3(16,16), 256, 0, stream>>>(wq,  wq_t,  512, 512);
  k_transpose<<<dim3(16,16), 256, 0, stream>>>(wk,  wk_t,  512, 512);
  k_transpose<<<dim3(16,16), 256, 0, stream>>>(wv,  wv_t,  512, 512);
  k_transpose<<<dim3(16,16), 256, 0, stream>>>(wf,  wf_t,  512, 512);
  k_transpose<<<dim3(64,16), 256, 0, stream>>>(wup, wup_t, 512, 2048);
  k_transpose<<<dim3(16,64), 256, 0, stream>>>(wdn, wdn_t, 2048, 512);
  // LN1 + cond -> hp (pad rows zero)
  k_lncond<<<NP/4, 256, 0, stream>>>(x, cond, hp, NNODES);
  // QKV projections
  k_gemm<<<dim3(322,4), 256, 0, stream>>>(hp, 512, wq_t, 512, nullptr, nullptr, 0,
                                          qbuf, 512, NP, 8, 0);
  k_gemm<<<dim3(322,4), 256, 0, stream>>>(hp, 512, wk_t, 512, nullptr, nullptr, 0,
                                          kbuf, 512, NP, 8, 0);
  k_gemm<<<dim3(322,4), 256, 0, stream>>>(hp, 512, wv_t, 512, nullptr, nullptr, 0,
                                          vtbuf, NP, NP, 8, GF_TRANS);
  // attention (writes o into hp)
  k_attn<<<dim3(NBLK,2,NH), 512, 0, stream>>>(qbuf, kbuf, vtbuf, hp);
  // final projection + residual -> x1 (fp32)
  k_gemm<<<dim3(322,4), 256, 0, stream>>>(hp, 512, wf_t, 512, bfin, x, 512,
                                          x1, 512, NNODES, 8, GF_F32);
  // LN2 + cond -> h2 (qbuf), pad rows zero
  k_lncond<<<NP/4, 256, 0, stream>>>(x1, cond, qbuf, NNODES);
  // FFW in two 1024-wide halves (u overlays hp+kbuf)
  k_gemm<<<dim3(322,8), 256, 0, stream>>>(qbuf, 512, wup_t, 512, bup, nullptr, 0,
                                          ubuf, 1024, NP, 8, GF_GELU);
  k_gemm<<<dim3(322,4), 256, 0, stream>>>(ubuf, 1024, wdn_t, 2048, bdn, x1, 512,
                                          out, 512, NNODES, 16, GF_F32);
  k_gemm<<<dim3(322,8), 256, 0, stream>>>(qbuf, 512, wup_t + (size_t)1024*512, 512,
                                          bup + 1024, nullptr, 0,
                                          ubuf, 1024, NP, 8, GF_GELU);
  k_gemm<<<dim3(322,4), 256, 0, stream>>>(ubuf, 1024, wdn_t + 1024, 2048, nullptr,
                                          out, 512, out, 512, NNODES, 16, GF_F32);
}